// Round 15
// baseline (219.893 us; speedup 1.0000x reference)
//
#include <hip/hip_runtime.h>
#include <hip/hip_bf16.h>

// SupConLoss, B=8192, D=128, T=0.1. Output: single fp32 scalar.
//
// Pipeline (3 launches):
//   1) supcon_convert — dtype detection; features -> bf16 ws copy in
//      MFMA-FRAGMENT ORDER (frag[((T*4+g)<<10)+lane*16] holds
//      B[n=lane&15][k=g*32+(lane>>4)*8+j]) so every fragment load in main
//      is ONE contiguous 1KB global_load_dwordx4. Labels -> int32; accbuf
//      (ticket) zeroed.
//   2) supcon_main    — SYMMETRIC fused GEMM: S=F.F^T is symmetric, so each
//      off-diagonal 256x256 chunk-pair (bi<bj) is computed ONCE with a DUAL
//      epilogue: row-side e/p for rows of bi (over cols of bj) AND col-side
//      e/p for rows of bj (column sums of the same exp'd tile, via
//      shfl_xor(16/32) + one-shot LDS slots + end-of-block merge).
//      MFMA+exp2 work -> 51.5%. Partial-slot scheme (64 slots of 128 cols):
//      block (bi,bj,h) writes row-side to slot 2bj+h, col-side to slot 2bi
//      + explicit zeros to 2bi+1; every (slot,row) written exactly once ->
//      reduce stays a plain 64-term sum (no zero-init of ws needed).
//      Wave geometry = r14's proven config (64 rows/wave, afrag[4][4],
//      2-state reg rotation, barrier-free loop, ~175 VGPR band).
//   3) supcon_reduce  — 64-slot partial sum -> loss. n_i from exact label
//      histogram. Diagonal removed exactly (same exp2 on same input).
//      Last-block-atomic finalization (ticket zeroed by convert).
//
// Math: with ANY fixed shift M, per row i:
//   mean_log_prob_i = 10*p_i/n_i - M - log(sum_{j!=i} exp(s_ij - M))
// (shift cancels; M=10.5 >= max s_ij for unit-norm). exp folded to exp2.
// Symmetry exactness: dot(a_i,a_j) and dot(a_j,a_i) feed identical products
// through the same MFMA reduction tree -> bitwise-equal s; only the order
// of e's accumulation over j changes (~1e-5 on the loss, well in tolerance).
//
// History:
//  r1: forced occupancy -> spill. r2-r4: LDS-staged ~35-46us (barrier
//      lockstep). r5-r7,r10: class-sum side kernels all latency traps ->
//      p folded into main. r8: sched_barrier -> spill (WRITE 74MB).
//  r9/r10: strided B-loads -> 46us. r12: fragment-order pre-swizzle ->
//      main ~30us, total 92.4 (best). r13: deeper prefetch REGRESSED
//      (VGPR>128 cliff). r14: 64 rows/wave NULL (93.9) -> neither prefetch
//      depth nor L1 redundancy is the stall; it scales per-tile. This
//      round: halve the tiles themselves via symmetry.

#define BB 8192
#define DD 128
#define NCLS 100
#define NCH 32                // 256-row chunks
#define NC2 64                // partial slots (128-col units)
#define NT 8                  // col-tiles of 16 per block (128 cols)
#define TEMP_INV 10.0f
#define MSHIFT 10.5f
#define C1F 14.426950408889634f    /* 10*log2(e)    */
#define C2F -15.148297929334116f   /* -10.5*log2(e) */

typedef __bf16 bf16x8 __attribute__((ext_vector_type(8)));
typedef float floatx4 __attribute__((ext_vector_type(4)));

__device__ inline float fast_exp2(float x) {
#if __has_builtin(__builtin_amdgcn_exp2f)
    return __builtin_amdgcn_exp2f(x);
#else
    return exp2f(x);
#endif
}

__device__ inline unsigned short f2bf(float f) {           // RTNE fp32->bf16
    unsigned u = __float_as_uint(f);
    return (unsigned short)((u + 0x7FFFu + ((u >> 16) & 1u)) >> 16);
}

// ---- 1) canonicalize into fragment order (+ detect + labels + zero) ----
// Grid 512 x 256: thread handles one 16B output granule G:
//   T = G>>8 (col-tile), g = (G>>6)&3 (k-chunk), l = G&63 (lane slot)
//   col = T*16 + (l&15); kb = g*32 + (l>>4)*8; 8 bf16 from row `col`.
__global__ __launch_bounds__(256) void supcon_convert(
    const void* __restrict__ fin, const void* __restrict__ lin,
    unsigned short* __restrict__ frag, int* __restrict__ lab,
    float* __restrict__ accbuf)
{
    // Per-wave dtype detection (header reads broadcast from L1).
    int lane = threadIdx.x & 63;
    unsigned ue = ((unsigned)((const unsigned short*)fin)[2 * lane]) << 16;
    float fe = __uint_as_float(ue);
    float ve = fe * fe;
    int odd_or = ((const int*)lin)[2 * lane + 1];
#pragma unroll
    for (int m = 1; m < 64; m <<= 1) {
        ve += __shfl_xor(ve, m, 64);
        odd_or |= __shfl_xor(odd_or, m, 64);
    }
    // true bf16 unit rows: sum sq of 64 even slots of row 0 is ~0.5.
    bool f_bf16 = (ve > 0.05f) && (ve < 4.0f);   // NaN-safe: NaN -> false
    bool l_i64  = (odd_or == 0);

    int G = blockIdx.x * 256 + threadIdx.x;      // 131072 granules x 16B
    int T = G >> 8;
    int g = (G >> 6) & 3;
    int l = G & 63;
    int col = T * 16 + (l & 15);
    int kb  = g * 32 + ((l >> 4) << 3);

    ushort4 o0, o1;
    if (!f_bf16) {
        const float4* src = (const float4*)((const float*)fin + (size_t)col * DD + kb);
        float4 a = src[0], b = src[1];
        o0.x = f2bf(a.x); o0.y = f2bf(a.y); o0.z = f2bf(a.z); o0.w = f2bf(a.w);
        o1.x = f2bf(b.x); o1.y = f2bf(b.y); o1.z = f2bf(b.z); o1.w = f2bf(b.w);
    } else {
        const ushort4* src = (const ushort4*)((const unsigned short*)fin + (size_t)col * DD + kb);
        o0 = src[0]; o1 = src[1];
    }
    ushort4* dst = (ushort4*)(frag + (size_t)G * 8);   // coalesced 16B store
    dst[0] = o0; dst[1] = o1;

    const int* L = (const int*)lin;
    if (blockIdx.x < 32) {
        int li = blockIdx.x * 256 + threadIdx.x;
        lab[li] = l_i64 ? L[2 * li] : L[li];
    }
    if (blockIdx.x == 0 && threadIdx.x == 0) {   // zero last-block finals
        accbuf[0] = 0.0f;                        // loss sum
        accbuf[1] = 0.0f;                        // valid count
        ((unsigned*)accbuf)[2] = 0u;             // ticket
    }
}

// Load B fragments + column labels for col-tile `t`: 4 coalesced 1KB loads
// + one 64B label segment.
#define LOADT(bb, lc, t)                                                      \
    {                                                                         \
        const unsigned char* fb =                                             \
            Fbc + ((size_t)((ctile0 + (t)) * 4) << 10) + lane * 16;           \
        _Pragma("unroll")                                                     \
        for (int k = 0; k < 4; ++k)                                           \
            bb[k] = *(const bf16x8*)(fb + (k << 10));                         \
        lc = lab[colbase0 + (t) * 16 + l16];                                  \
    }

// Compute one 16-col tile x 64 rows: 16 MFMA + diag + DUAL epilogue.
#define COMPT(bb, lc, t)                                                      \
    {                                                                         \
        int colbase = colbase0 + (t) * 16;                                    \
        floatx4 acc[4];                                                       \
        _Pragma("unroll")                                                     \
        for (int ti = 0; ti < 4; ++ti) acc[ti] = (floatx4){0.f,0.f,0.f,0.f};  \
        _Pragma("unroll")                                                     \
        for (int k = 0; k < 4; ++k) {                                         \
            _Pragma("unroll")                                                 \
            for (int ti = 0; ti < 4; ++ti)                                    \
                acc[ti] = __builtin_amdgcn_mfma_f32_16x16x32_bf16(            \
                    afrag[ti][k], bb[k], acc[ti], 0, 0, 0);                   \
        }                                                                     \
        /* Diagonal capture: fires only in diag blocks (col==row range). */   \
        {                                                                     \
            unsigned u = (unsigned)(colbase - (rowbase + wid * 64));          \
            if (u < 64u) {                                                    \
                _Pragma("unroll")                                             \
                for (int ti2 = 0; ti2 < 4; ++ti2) {                           \
                    if (u == (unsigned)(ti2 * 16)) {                          \
                        _Pragma("unroll")                                     \
                        for (int r = 0; r < 4; ++r)                           \
                            if (l16 == quad * 4 + r)                          \
                                diag[colbase + l16] = acc[ti2][r];            \
                    }                                                         \
                }                                                             \
            }                                                                 \
        }                                                                     \
        float cE = 0.0f, cP = 0.0f;                                           \
        _Pragma("unroll")                                                     \
        for (int ti = 0; ti < 4; ++ti) {                                      \
            _Pragma("unroll")                                                 \
            for (int r = 0; r < 4; ++r) {                                     \
                /* C/D: D[row=quad*4+r][col=l16] (m89/m91 verified) */        \
                int i = ti * 4 + r;                                           \
                float a = acc[ti][r];                                         \
                float ex = fast_exp2(__builtin_fmaf(a, C1F, C2F));            \
                e_acc[i] += ex;                                               \
                float peq = ((lc) == lab_row[i]) ? 1.0f : 0.0f;               \
                p_acc[i] = __builtin_fmaf(peq, a, p_acc[i]);                  \
                cE += ex;                                                     \
                cP = __builtin_fmaf(peq, a, cP);                              \
            }                                                                 \
        }                                                                     \
        if (!isdiag) {                                                        \
            /* column sums across the 4 quads sharing l16 */                  \
            cE += __shfl_xor(cE, 16, 64); cE += __shfl_xor(cE, 32, 64);       \
            cP += __shfl_xor(cP, 16, 64); cP += __shfl_xor(cP, 32, 64);       \
            if (quad == 0) {                                                  \
                ldsE[wid][(t) * 16 + l16] = cE;   /* one writer per slot */   \
                ldsP[wid][(t) * 16 + l16] = cP;                               \
            }                                                                 \
        }                                                                     \
    }

// ---- 2) symmetric fused GEMM + dual e/p partials ----
__global__ __launch_bounds__(256, 2) void supcon_main(
    const unsigned short* __restrict__ Fb, const int* __restrict__ lab,
    float* __restrict__ e_part, float* __restrict__ p_part,
    float* __restrict__ diag)
{
    __shared__ float ldsE[4][128], ldsP[4][128];  // per-wave col partials

    const int tid  = threadIdx.x;
    const int lane = tid & 63;
    const int wid  = tid >> 6;                   // wave owns 64 rows
    const int quad = lane >> 4;
    const int l16  = lane & 15;

    // Decode triangle pair (bi <= bj) + column half.
    int pairIdx = blockIdx.x >> 1;
    int h       = blockIdx.x & 1;
    int bi = 0;
    {
        unsigned k = (unsigned)pairIdx;
        while (k >= (unsigned)(NCH - bi)) { k -= (NCH - bi); ++bi; }
        pairIdx = (int)k;
    }
    const int bj = bi + pairIdx;
    const bool isdiag = (bi == bj);

    const int rowbase  = bi * 256;
    const int colbase0 = bj * 256 + h * 128;
    const int ctile0   = colbase0 >> 4;

    const unsigned char* Fbc = (const unsigned char*)Fb;

    // A fragments (4 row-tiles x 4 k-chunks) — coalesced 1KB loads.
    bf16x8 afrag[4][4];
#pragma unroll
    for (int ti = 0; ti < 4; ++ti) {
        int rt = (rowbase >> 4) + wid * 4 + ti;
        const unsigned char* fa = Fbc + ((size_t)(rt * 4) << 10) + lane * 16;
#pragma unroll
        for (int k = 0; k < 4; ++k)
            afrag[ti][k] = *(const bf16x8*)(fa + (k << 10));
    }

    int lab_row[16];
#pragma unroll
    for (int ti = 0; ti < 4; ++ti)
#pragma unroll
        for (int r = 0; r < 4; ++r)
            lab_row[ti * 4 + r] = lab[rowbase + wid * 64 + ti * 16 + quad * 4 + r];

    float e_acc[16], p_acc[16];
#pragma unroll
    for (int i = 0; i < 16; ++i) { e_acc[i] = 0.0f; p_acc[i] = 0.0f; }

    // Two named B states (rule #20: static names, never runtime-indexed).
    bf16x8 b0[4], b1[4];
    int lc0, lc1;
    LOADT(b0, lc0, 0);

    for (int t = 0; t < NT; t += 2) {
        LOADT(b1, lc1, t + 1);           // issue-early
        COMPT(b0, lc0, t);               // use-late
        if (t + 2 < NT) LOADT(b0, lc0, t + 2);
        COMPT(b1, lc1, t + 1);
    }

    // Row-side: waves own disjoint rows -> shfl-reduce over 16 col-lanes,
    // write slot c = 2*bj + h.
#pragma unroll
    for (int i = 0; i < 16; ++i) {
        float e = e_acc[i], p = p_acc[i];
#pragma unroll
        for (int m = 1; m < 16; m <<= 1) {
            e += __shfl_xor(e, m, 64);
            p += __shfl_xor(p, m, 64);
        }
        if (l16 == 0) {
            int row = rowbase + wid * 64 + (i >> 2) * 16 + quad * 4 + (i & 3);
            size_t base = (size_t)(2 * bj + h) * BB + row;
            e_part[base] = e;
            p_part[base] = p;
        }
    }

    // Col-side (off-diag only): merge the 4 per-wave LDS slices, write
    // slot 2*bi (full 256-row sums) + explicit zeros to slot 2*bi+1.
    if (!isdiag) {
        __syncthreads();
        if (tid < 128) {
            float e = ldsE[0][tid] + ldsE[1][tid] + ldsE[2][tid] + ldsE[3][tid];
            float p = ldsP[0][tid] + ldsP[1][tid] + ldsP[2][tid] + ldsP[3][tid];
            int j = colbase0 + tid;
            e_part[(size_t)(2 * bi) * BB + j] = e;
            p_part[(size_t)(2 * bi) * BB + j] = p;
            e_part[(size_t)(2 * bi + 1) * BB + j] = 0.0f;
            p_part[(size_t)(2 * bi + 1) * BB + j] = 0.0f;
        }
    }
}

// ---- 3) 64-slot partials -> scalar loss ----
__global__ __launch_bounds__(256) void supcon_reduce(
    const float* __restrict__ e_part, const float* __restrict__ p_part,
    const int* __restrict__ labels, const float* __restrict__ diag,
    float* __restrict__ accbuf, float* __restrict__ out)
{
    // Exact per-class counts over the whole batch (labels in [0,100)).
    __shared__ int cnt[128];
    if (threadIdx.x < 128) cnt[threadIdx.x] = 0;
    __syncthreads();
    for (int i = threadIdx.x; i < BB; i += 256)
        atomicAdd(&cnt[labels[i]], 1);
    __syncthreads();

    int row = blockIdx.x * 256 + threadIdx.x;    // grid 32
    float e = 0.f, p = 0.f;
#pragma unroll 8
    for (int c = 0; c < NC2; ++c) {
        size_t idx = (size_t)c * BB + row;
        e += e_part[idx]; p += p_part[idx];
    }
    // exact diagonal removal (e: same exp2 instruction on same input as main)
    float d = diag[row];
    e -= fast_exp2(__builtin_fmaf(d, C1F, C2F));
    p -= d;
    int n_i = cnt[labels[row]] - 1;              // integer-exact positive count

    float contrib = 0.f, vld = 0.f;
    if (n_i > 0) {
        vld = 1.0f;
        contrib = -(p * TEMP_INV / (float)n_i - MSHIFT - logf(e));
    }
#pragma unroll
    for (int m = 1; m < 64; m <<= 1) {
        contrib += __shfl_xor(contrib, m, 64);
        vld     += __shfl_xor(vld, m, 64);
    }
    __shared__ float rl[4], rv[4];
    int lane = threadIdx.x & 63, w = threadIdx.x >> 6;
    if (lane == 0) { rl[w] = contrib; rv[w] = vld; }
    __syncthreads();
    if (threadIdx.x == 0) {
        float L = rl[0] + rl[1] + rl[2] + rl[3];
        float V = rv[0] + rv[1] + rv[2] + rv[3];
        atomicAdd(&accbuf[0], L);
        atomicAdd(&accbuf[1], V);
        __threadfence();
        unsigned t = atomicAdd((unsigned*)accbuf + 2, 1u);
        if (t == 31u) {                      // last block: all adds fenced+done
            float Ls = atomicAdd(&accbuf[0], 0.0f);
            float Vs = atomicAdd(&accbuf[1], 0.0f);
            out[0] = (Vs > 0.5f) ? (Ls / Vs) : 0.0f;
        }
    }
}

extern "C" void kernel_launch(void* const* d_in, const int* in_sizes, int n_in,
                              void* d_out, int out_size, void* d_ws, size_t ws_size,
                              hipStream_t stream)
{
    const void* Fin = d_in[0];
    const void* Lin = d_in[1];

    // ws layout (~6.2 MB)
    unsigned short* frag = (unsigned short*)d_ws;                         // 2 MB fragment-order bf16
    int*   lab      = (int*)((char*)d_ws + (size_t)BB * DD * 2);          // 32 KB
    float* e_part   = (float*)((char*)lab + (size_t)BB * 4);              // NC2*B floats (2 MB)
    float* p_part   = e_part + (size_t)NC2 * BB;                          // 2 MB
    float* diag     = p_part + (size_t)NC2 * BB;                          // B floats
    float* accbuf   = diag + BB;                                          // 3 slots

    supcon_convert<<<BB * DD / 8 / 256, 256, 0, stream>>>(Fin, Lin, frag, lab, accbuf);

    // 528 triangle pairs x 2 column halves.
    supcon_main<<<(NCH * (NCH + 1) / 2) * 2, 256, 0, stream>>>(
        frag, lab, e_part, p_part, diag);

    supcon_reduce<<<32, 256, 0, stream>>>(e_part, p_part, lab, diag, accbuf, (float*)d_out);
}

// Round 16
// 103.297 us; speedup vs baseline: 2.1287x; 2.1287x over previous
//
#include <hip/hip_runtime.h>
#include <hip/hip_bf16.h>

// SupConLoss, B=8192, D=128, T=0.1. Output: single fp32 scalar.
//
// Pipeline (3 launches):
//   1) supcon_convert — dtype detection; features -> bf16 ws copy in
//      MFMA-FRAGMENT ORDER (frag[((T*4+g)<<10)+lane*16] holds
//      B[n=lane&15][k=g*32+(lane>>4)*8+j]) so every fragment load in main
//      is ONE contiguous 1KB global_load_dwordx4. Labels -> int32; accbuf
//      (ticket) zeroed.
//   2) supcon_main    — SYMMETRIC fused GEMM on the r12 register geometry.
//      S=F.F^T symmetric: 64 chunks of 128 rows -> 2080 triangle pairs
//      (bi<=bj), one 256-thread block each (4 waves x 32 rows x 128 cols =
//      exactly r12's per-wave shape, measured VGPR 104 + ~8 for the dual
//      epilogue -> stays under the 128 cliff; r15's spill was the 64-row
//      geometry at ~176 live regs, not the symmetry idea). Off-diag pairs
//      get a DUAL epilogue: row-side e/p for rows of bi; col-side e/p for
//      rows of bj via shfl_xor(16/32) column sums + one-shot LDS slots +
//      one end-of-block merge. Slot scheme is exact: row r in chunk b is
//      written by row-side slots bj in [b,64) and col-side slots bi in
//      [0,b) -> all 64 slots exactly once, no zero-fill. Diag pairs
//      compute their full 128x128 square, row-side only. MFMA+exp2 -> 51%.
//   3) supcon_reduce  — 64-slot partial sum -> loss. n_i from exact label
//      histogram. Diagonal removed exactly (same exp2 on same input).
//      Last-block-atomic finalization (ticket zeroed by convert).
//
// Math: with ANY fixed shift M, per row i:
//   mean_log_prob_i = 10*p_i/n_i - M - log(sum_{j!=i} exp(s_ij - M))
// (shift cancels; M=10.5 >= max s_ij for unit-norm). exp folded to exp2.
// Symmetry exactness: dot(a_i,a_j)=dot(a_j,a_i) bitwise through the same
// MFMA tree; only e/p accumulation ORDER changes (~1e-5 on the loss).
//
// History:
//  r1: forced occupancy -> spill. r2-r4: LDS-staged ~35-46us (barrier
//      lockstep). r5-r7,r10: class-sum side kernels all latency traps.
//  r8: sched_barrier -> spill (WRITE 74MB). r9/r10: strided B-loads 46us.
//  r12: fragment-order pre-swizzle: main ~30us, total 92.4 (best).
//  r13: deeper prefetch REGRESSED (VGPR>128 cliff, 96.3).
//  r14: 64 rows/wave NULL (93.9) -> stall scales per-tile, not L1/prefetch.
//  r15: symmetry on 64-row geometry -> SPILL (WRITE 212MB, main 144us).
//      This round: symmetry on the PROVEN 32-row geometry.

#define BB 8192
#define DD 128
#define NCLS 100
#define NCH 64                // 128-row chunks
#define NPAIR (NCH * (NCH + 1) / 2)   // 2080 blocks
#define NC2 64                // partial slots (one per chunk)
#define NT 8                  // col-tiles of 16 per block (128 cols)
#define TEMP_INV 10.0f
#define MSHIFT 10.5f
#define C1F 14.426950408889634f    /* 10*log2(e)    */
#define C2F -15.148297929334116f   /* -10.5*log2(e) */

typedef __bf16 bf16x8 __attribute__((ext_vector_type(8)));
typedef float floatx4 __attribute__((ext_vector_type(4)));

__device__ inline float fast_exp2(float x) {
#if __has_builtin(__builtin_amdgcn_exp2f)
    return __builtin_amdgcn_exp2f(x);
#else
    return exp2f(x);
#endif
}

__device__ inline unsigned short f2bf(float f) {           // RTNE fp32->bf16
    unsigned u = __float_as_uint(f);
    return (unsigned short)((u + 0x7FFFu + ((u >> 16) & 1u)) >> 16);
}

// ---- 1) canonicalize into fragment order (+ detect + labels + zero) ----
// Grid 512 x 256: thread handles one 16B output granule G:
//   T = G>>8 (col-tile), g = (G>>6)&3 (k-chunk), l = G&63 (lane slot)
//   col = T*16 + (l&15); kb = g*32 + (l>>4)*8; 8 bf16 from row `col`.
__global__ __launch_bounds__(256) void supcon_convert(
    const void* __restrict__ fin, const void* __restrict__ lin,
    unsigned short* __restrict__ frag, int* __restrict__ lab,
    float* __restrict__ accbuf)
{
    // Per-wave dtype detection (header reads broadcast from L1).
    int lane = threadIdx.x & 63;
    unsigned ue = ((unsigned)((const unsigned short*)fin)[2 * lane]) << 16;
    float fe = __uint_as_float(ue);
    float ve = fe * fe;
    int odd_or = ((const int*)lin)[2 * lane + 1];
#pragma unroll
    for (int m = 1; m < 64; m <<= 1) {
        ve += __shfl_xor(ve, m, 64);
        odd_or |= __shfl_xor(odd_or, m, 64);
    }
    // true bf16 unit rows: sum sq of 64 even slots of row 0 is ~0.5.
    bool f_bf16 = (ve > 0.05f) && (ve < 4.0f);   // NaN-safe: NaN -> false
    bool l_i64  = (odd_or == 0);

    int G = blockIdx.x * 256 + threadIdx.x;      // 131072 granules x 16B
    int T = G >> 8;
    int g = (G >> 6) & 3;
    int l = G & 63;
    int col = T * 16 + (l & 15);
    int kb  = g * 32 + ((l >> 4) << 3);

    ushort4 o0, o1;
    if (!f_bf16) {
        const float4* src = (const float4*)((const float*)fin + (size_t)col * DD + kb);
        float4 a = src[0], b = src[1];
        o0.x = f2bf(a.x); o0.y = f2bf(a.y); o0.z = f2bf(a.z); o0.w = f2bf(a.w);
        o1.x = f2bf(b.x); o1.y = f2bf(b.y); o1.z = f2bf(b.z); o1.w = f2bf(b.w);
    } else {
        const ushort4* src = (const ushort4*)((const unsigned short*)fin + (size_t)col * DD + kb);
        o0 = src[0]; o1 = src[1];
    }
    ushort4* dst = (ushort4*)(frag + (size_t)G * 8);   // coalesced 16B store
    dst[0] = o0; dst[1] = o1;

    const int* L = (const int*)lin;
    if (blockIdx.x < 32) {
        int li = blockIdx.x * 256 + threadIdx.x;
        lab[li] = l_i64 ? L[2 * li] : L[li];
    }
    if (blockIdx.x == 0 && threadIdx.x == 0) {   // zero last-block finals
        accbuf[0] = 0.0f;                        // loss sum
        accbuf[1] = 0.0f;                        // valid count
        ((unsigned*)accbuf)[2] = 0u;             // ticket
    }
}

// Load B fragments + column labels for col-tile `t`: 4 coalesced 1KB loads
// + one 64B label segment.
#define LOADT(bb, lc, t)                                                      \
    {                                                                         \
        const unsigned char* fb =                                             \
            Fbc + ((size_t)((ctile0 + (t)) * 4) << 10) + lane * 16;           \
        _Pragma("unroll")                                                     \
        for (int k = 0; k < 4; ++k)                                           \
            bb[k] = *(const bf16x8*)(fb + (k << 10));                         \
        lc = lab[colbase0 + (t) * 16 + l16];                                  \
    }

// Compute one 16-col tile x 32 rows: 8 MFMA + diag + DUAL epilogue.
#define COMPT(bb, lc, t)                                                      \
    {                                                                         \
        int colbase = colbase0 + (t) * 16;                                    \
        floatx4 acc[2];                                                       \
        acc[0] = (floatx4){0.f, 0.f, 0.f, 0.f};                               \
        acc[1] = (floatx4){0.f, 0.f, 0.f, 0.f};                               \
        _Pragma("unroll")                                                     \
        for (int k = 0; k < 4; ++k) {                                         \
            acc[0] = __builtin_amdgcn_mfma_f32_16x16x32_bf16(                 \
                afrag[0][k], bb[k], acc[0], 0, 0, 0);                         \
            acc[1] = __builtin_amdgcn_mfma_f32_16x16x32_bf16(                 \
                afrag[1][k], bb[k], acc[1], 0, 0, 0);                         \
        }                                                                     \
        /* Diagonal capture: fires only in diag blocks (col==row range). */   \
        {                                                                     \
            unsigned u = (unsigned)(colbase - (rowbase + wid * 32));          \
            if (u < 32u) {                                                    \
                _Pragma("unroll")                                             \
                for (int ti2 = 0; ti2 < 2; ++ti2) {                           \
                    if (u == (unsigned)(ti2 * 16)) {                          \
                        _Pragma("unroll")                                     \
                        for (int r = 0; r < 4; ++r)                           \
                            if (l16 == quad * 4 + r)                          \
                                diag[colbase + l16] = acc[ti2][r];            \
                    }                                                         \
                }                                                             \
            }                                                                 \
        }                                                                     \
        float cE = 0.0f, cP = 0.0f;                                           \
        _Pragma("unroll")                                                     \
        for (int ti = 0; ti < 2; ++ti) {                                      \
            _Pragma("unroll")                                                 \
            for (int r = 0; r < 4; ++r) {                                     \
                /* C/D: D[row=quad*4+r][col=l16] (m89/m91 verified) */        \
                int i = ti * 4 + r;                                           \
                float a = acc[ti][r];                                         \
                float ex = fast_exp2(__builtin_fmaf(a, C1F, C2F));            \
                e_acc[i] += ex;                                               \
                float peq = ((lc) == lab_row[i]) ? 1.0f : 0.0f;               \
                p_acc[i] = __builtin_fmaf(peq, a, p_acc[i]);                  \
                cE += ex;                                                     \
                cP = __builtin_fmaf(peq, a, cP);                              \
            }                                                                 \
        }                                                                     \
        if (!isdiag) {                                                        \
            /* column sums across the 4 quads sharing l16 */                  \
            cE += __shfl_xor(cE, 16, 64); cE += __shfl_xor(cE, 32, 64);       \
            cP += __shfl_xor(cP, 16, 64); cP += __shfl_xor(cP, 32, 64);       \
            if (quad == 0) {                                                  \
                ldsE[wid][(t) * 16 + l16] = cE;   /* one writer per slot */   \
                ldsP[wid][(t) * 16 + l16] = cP;                               \
            }                                                                 \
        }                                                                     \
    }

// ---- 2) symmetric fused GEMM + dual e/p partials (r12 geometry) ----
__global__ __launch_bounds__(256, 2) void supcon_main(
    const unsigned short* __restrict__ Fb, const int* __restrict__ lab,
    float* __restrict__ e_part, float* __restrict__ p_part,
    float* __restrict__ diag)
{
    __shared__ float ldsE[4][128], ldsP[4][128];  // per-wave col partials

    const int tid  = threadIdx.x;
    const int lane = tid & 63;
    const int wid  = tid >> 6;                   // wave owns 32 rows
    const int quad = lane >> 4;
    const int l16  = lane & 15;

    // Decode triangle pair (bi <= bj).
    int bi = 0;
    int bj;
    {
        unsigned k = (unsigned)blockIdx.x;
        while (k >= (unsigned)(NCH - bi)) { k -= (NCH - bi); ++bi; }
        bj = bi + (int)k;
    }
    const bool isdiag = (bi == bj);

    const int rowbase  = bi * 128;
    const int colbase0 = bj * 128;
    const int ctile0   = colbase0 >> 4;

    const unsigned char* Fbc = (const unsigned char*)Fb;

    // A fragments (2 row-tiles x 4 k-chunks) — coalesced 1KB loads.
    bf16x8 afrag[2][4];
#pragma unroll
    for (int ti = 0; ti < 2; ++ti) {
        int rt = (rowbase >> 4) + wid * 2 + ti;
        const unsigned char* fa = Fbc + ((size_t)(rt * 4) << 10) + lane * 16;
#pragma unroll
        for (int k = 0; k < 4; ++k)
            afrag[ti][k] = *(const bf16x8*)(fa + (k << 10));
    }

    int lab_row[8];
#pragma unroll
    for (int ti = 0; ti < 2; ++ti)
#pragma unroll
        for (int r = 0; r < 4; ++r)
            lab_row[ti * 4 + r] = lab[rowbase + wid * 32 + ti * 16 + quad * 4 + r];

    float e_acc[8], p_acc[8];
#pragma unroll
    for (int i = 0; i < 8; ++i) { e_acc[i] = 0.0f; p_acc[i] = 0.0f; }

    // Two named B states (rule #20: static names, never runtime-indexed).
    bf16x8 b0[4], b1[4];
    int lc0, lc1;
    LOADT(b0, lc0, 0);

    for (int t = 0; t < NT; t += 2) {
        LOADT(b1, lc1, t + 1);           // issue-early
        COMPT(b0, lc0, t);               // use-late
        if (t + 2 < NT) LOADT(b0, lc0, t + 2);
        COMPT(b1, lc1, t + 1);
    }

    // Row-side: waves own disjoint rows -> shfl-reduce over 16 col-lanes,
    // write slot bj.
#pragma unroll
    for (int i = 0; i < 8; ++i) {
        float e = e_acc[i], p = p_acc[i];
#pragma unroll
        for (int m = 1; m < 16; m <<= 1) {
            e += __shfl_xor(e, m, 64);
            p += __shfl_xor(p, m, 64);
        }
        if (l16 == 0) {
            int row = rowbase + wid * 32 + (i >> 2) * 16 + quad * 4 + (i & 3);
            size_t base = (size_t)bj * BB + row;
            e_part[base] = e;
            p_part[base] = p;
        }
    }

    // Col-side (off-diag only): merge the 4 per-wave LDS slices -> slot bi.
    // Block-uniform condition -> barrier is safe.
    if (!isdiag) {
        __syncthreads();
        if (tid < 128) {
            float e = ldsE[0][tid] + ldsE[1][tid] + ldsE[2][tid] + ldsE[3][tid];
            float p = ldsP[0][tid] + ldsP[1][tid] + ldsP[2][tid] + ldsP[3][tid];
            int j = colbase0 + tid;
            e_part[(size_t)bi * BB + j] = e;
            p_part[(size_t)bi * BB + j] = p;
        }
    }
}

// ---- 3) 64-slot partials -> scalar loss ----
__global__ __launch_bounds__(256) void supcon_reduce(
    const float* __restrict__ e_part, const float* __restrict__ p_part,
    const int* __restrict__ labels, const float* __restrict__ diag,
    float* __restrict__ accbuf, float* __restrict__ out)
{
    // Exact per-class counts over the whole batch (labels in [0,100)).
    __shared__ int cnt[128];
    if (threadIdx.x < 128) cnt[threadIdx.x] = 0;
    __syncthreads();
    for (int i = threadIdx.x; i < BB; i += 256)
        atomicAdd(&cnt[labels[i]], 1);
    __syncthreads();

    int row = blockIdx.x * 256 + threadIdx.x;    // grid 32
    float e = 0.f, p = 0.f;
#pragma unroll 8
    for (int c = 0; c < NC2; ++c) {
        size_t idx = (size_t)c * BB + row;
        e += e_part[idx]; p += p_part[idx];
    }
    // exact diagonal removal (e: same exp2 instruction on same input as main)
    float d = diag[row];
    e -= fast_exp2(__builtin_fmaf(d, C1F, C2F));
    p -= d;
    int n_i = cnt[labels[row]] - 1;              // integer-exact positive count

    float contrib = 0.f, vld = 0.f;
    if (n_i > 0) {
        vld = 1.0f;
        contrib = -(p * TEMP_INV / (float)n_i - MSHIFT - logf(e));
    }
#pragma unroll
    for (int m = 1; m < 64; m <<= 1) {
        contrib += __shfl_xor(contrib, m, 64);
        vld     += __shfl_xor(vld, m, 64);
    }
    __shared__ float rl[4], rv[4];
    int lane = threadIdx.x & 63, w = threadIdx.x >> 6;
    if (lane == 0) { rl[w] = contrib; rv[w] = vld; }
    __syncthreads();
    if (threadIdx.x == 0) {
        float L = rl[0] + rl[1] + rl[2] + rl[3];
        float V = rv[0] + rv[1] + rv[2] + rv[3];
        atomicAdd(&accbuf[0], L);
        atomicAdd(&accbuf[1], V);
        __threadfence();
        unsigned t = atomicAdd((unsigned*)accbuf + 2, 1u);
        if (t == 31u) {                      // last block: all adds fenced+done
            float Ls = atomicAdd(&accbuf[0], 0.0f);
            float Vs = atomicAdd(&accbuf[1], 0.0f);
            out[0] = (Vs > 0.5f) ? (Ls / Vs) : 0.0f;
        }
    }
}

extern "C" void kernel_launch(void* const* d_in, const int* in_sizes, int n_in,
                              void* d_out, int out_size, void* d_ws, size_t ws_size,
                              hipStream_t stream)
{
    const void* Fin = d_in[0];
    const void* Lin = d_in[1];

    // ws layout (~6.2 MB)
    unsigned short* frag = (unsigned short*)d_ws;                         // 2 MB fragment-order bf16
    int*   lab      = (int*)((char*)d_ws + (size_t)BB * DD * 2);          // 32 KB
    float* e_part   = (float*)((char*)lab + (size_t)BB * 4);              // NC2*B floats (2 MB)
    float* p_part   = e_part + (size_t)NC2 * BB;                          // 2 MB
    float* diag     = p_part + (size_t)NC2 * BB;                          // B floats
    float* accbuf   = diag + BB;                                          // 3 slots

    supcon_convert<<<BB * DD / 8 / 256, 256, 0, stream>>>(Fin, Lin, frag, lab, accbuf);

    supcon_main<<<NPAIR, 256, 0, stream>>>(frag, lab, e_part, p_part, diag);

    supcon_reduce<<<32, 256, 0, stream>>>(e_part, p_part, lab, diag, accbuf, (float*)d_out);
}

// Round 17
// 91.709 us; speedup vs baseline: 2.3977x; 1.1264x over previous
//
#include <hip/hip_runtime.h>
#include <hip/hip_bf16.h>

// SupConLoss, B=8192, D=128, T=0.1. Output: single fp32 scalar.
// r17 = REVERT to r12, the measured session optimum (92.4us total).
//
// Pipeline (3 launches):
//   1) supcon_convert — dtype detection (fp32 vs bf16 feats, i64 vs i32
//      labels); writes features ONCE in MFMA-FRAGMENT ORDER: for col-tile
//      T (16 cols) and k-chunk g, a 64-lane x 16B block at
//      frag[((T*4+g)<<10) + lane*16] = B[n=lane&15][k=g*32+(lane>>4)*8+j].
//      Every A/B fragment load in main is then ONE contiguous 1KB
//      global_load_dwordx4 (8 full 128B lines). Labels -> int32; accbuf
//      zeroed (graph-replay safe ticket).
//   2) supcon_main    — fused bf16-MFMA GEMM (F.F^T) + e/p accumulation.
//      Barrier-free, LDS-free, 2-state register rotation, 32 rows/wave,
//      VGPR 104 (16 waves/CU). Diagonal raw dot captured to ws. e/p
//      partials written per-wave (disjoint rows).
//   3) supcon_reduce  — e/p partials -> loss. n_i from exact label
//      histogram (n_i = cnt[lab_i]-1). Diagonal removed exactly (same exp2
//      instruction on same input). Last-block-atomic finalization.
//
// Math: with ANY fixed shift M, per row i:
//   mean_log_prob_i = 10*p_i/n_i - M - log(sum_{j!=i} exp(s_ij - M))
// (shift cancels; M=10.5 >= max s_ij for unit-norm). exp folded to exp2:
// exp(10a-10.5) = exp2(a*C1 + C2).
//
// Final search-tree summary (why this config is the optimum):
//  r1: forced occupancy -> VGPR spill. Never clamp below the live set.
//  r2-r4: LDS-staged variants 35-46us (2-phase barrier lockstep, m233).
//  r5-r7,r10: four side-kernel class-sum schemes, all 30-88us latency
//      traps -> p folded into main's epilogue.
//  r8: sched_barrier graft -> regalloc spill (WRITE 74MB, 144us cold).
//  r9/r10: reg-prefetch with STRIDED B-loads (16 half-lines/instr): 46us.
//  r12: fragment-order pre-swizzle (coalesced+barrier-free+prefetched):
//      main ~30us, total 92.4. BEST.
//  r13: 4-state prefetch: 96.3 (VGPR>128 cliff halves residency).
//  r14: 64 rows/wave (2x L1 reuse): 93.9 NULL.
//  r15: symmetry on 64-row geometry: SPILL (WRITE 212MB, main 144us).
//  r16: symmetry on r12 geometry: 103.3 — dual-epilogue VALU + 64-slot
//      reduce traffic exceed the MFMA savings (main is not MFMA-bound).
//  Fixed floor outside main: 41.5us harness workspace poison-fill +
//  ~8us convert + ~4us reduce + ~9us launch gaps.

#define BB 8192
#define DD 128
#define NCLS 100
#define NC 16                 // column chunks (grid.x): 1024 blocks
#define COLCHUNK (BB / NC)    // 512 cols per WG
#define NT (COLCHUNK / 16)    // 32 col-tiles of 16 (even: 2x-unrolled loop)
#define TEMP_INV 10.0f
#define MSHIFT 10.5f
#define C1F 14.426950408889634f    /* 10*log2(e)    */
#define C2F -15.148297929334116f   /* -10.5*log2(e) */

typedef __bf16 bf16x8 __attribute__((ext_vector_type(8)));
typedef float floatx4 __attribute__((ext_vector_type(4)));

__device__ inline float fast_exp2(float x) {
#if __has_builtin(__builtin_amdgcn_exp2f)
    return __builtin_amdgcn_exp2f(x);
#else
    return exp2f(x);
#endif
}

__device__ inline unsigned short f2bf(float f) {           // RTNE fp32->bf16
    unsigned u = __float_as_uint(f);
    return (unsigned short)((u + 0x7FFFu + ((u >> 16) & 1u)) >> 16);
}

// ---- 1) canonicalize into fragment order (+ detect + labels + zero) ----
// Grid 512 x 256: thread handles one 16B output granule G:
//   T = G>>8 (col-tile), g = (G>>6)&3 (k-chunk), l = G&63 (lane slot)
//   col = T*16 + (l&15); kb = g*32 + (l>>4)*8; 8 bf16 from row `col`.
__global__ __launch_bounds__(256) void supcon_convert(
    const void* __restrict__ fin, const void* __restrict__ lin,
    unsigned short* __restrict__ frag, int* __restrict__ lab,
    float* __restrict__ accbuf)
{
    // Per-wave dtype detection (header reads broadcast from L1).
    int lane = threadIdx.x & 63;
    unsigned ue = ((unsigned)((const unsigned short*)fin)[2 * lane]) << 16;
    float fe = __uint_as_float(ue);
    float ve = fe * fe;
    int odd_or = ((const int*)lin)[2 * lane + 1];
#pragma unroll
    for (int m = 1; m < 64; m <<= 1) {
        ve += __shfl_xor(ve, m, 64);
        odd_or |= __shfl_xor(odd_or, m, 64);
    }
    // true bf16 unit rows: sum sq of 64 even slots of row 0 is ~0.5.
    bool f_bf16 = (ve > 0.05f) && (ve < 4.0f);   // NaN-safe: NaN -> false
    bool l_i64  = (odd_or == 0);

    int G = blockIdx.x * 256 + threadIdx.x;      // 131072 granules x 16B
    int T = G >> 8;
    int g = (G >> 6) & 3;
    int l = G & 63;
    int col = T * 16 + (l & 15);
    int kb  = g * 32 + ((l >> 4) << 3);

    ushort4 o0, o1;
    if (!f_bf16) {
        const float4* src = (const float4*)((const float*)fin + (size_t)col * DD + kb);
        float4 a = src[0], b = src[1];
        o0.x = f2bf(a.x); o0.y = f2bf(a.y); o0.z = f2bf(a.z); o0.w = f2bf(a.w);
        o1.x = f2bf(b.x); o1.y = f2bf(b.y); o1.z = f2bf(b.z); o1.w = f2bf(b.w);
    } else {
        const ushort4* src = (const ushort4*)((const unsigned short*)fin + (size_t)col * DD + kb);
        o0 = src[0]; o1 = src[1];
    }
    ushort4* dst = (ushort4*)(frag + (size_t)G * 8);   // coalesced 16B store
    dst[0] = o0; dst[1] = o1;

    const int* L = (const int*)lin;
    if (blockIdx.x < 32) {
        int li = blockIdx.x * 256 + threadIdx.x;
        lab[li] = l_i64 ? L[2 * li] : L[li];
    }
    if (blockIdx.x == 0 && threadIdx.x == 0) {   // zero last-block finals
        accbuf[0] = 0.0f;                        // loss sum
        accbuf[1] = 0.0f;                        // valid count
        ((unsigned*)accbuf)[2] = 0u;             // ticket
    }
}

// Load B fragments for col-tile `t` (4 k-chunks): ONE coalesced 1KB load
// each, addr = fragbase + ((tile0+t)*4+k)*1024 + lane*16.
#define LOADF(bb, t)                                                          \
    {                                                                         \
        const unsigned char* fb =                                             \
            Fbc + ((size_t)((ctile0 + (t)) * 4) << 10) + lane * 16;           \
        _Pragma("unroll")                                                     \
        for (int k = 0; k < 4; ++k)                                           \
            bb[k] = *(const bf16x8*)(fb + (k << 10));                         \
    }

// Compute one 16-col tile from register set bb: 8 MFMA + diag + epilogue.
#define COMPUTE(bb, t)                                                        \
    {                                                                         \
        int colbase = colchunkbase + (t) * 16;                                \
        floatx4 acc[2];                                                       \
        acc[0] = (floatx4){0.f, 0.f, 0.f, 0.f};                               \
        acc[1] = (floatx4){0.f, 0.f, 0.f, 0.f};                               \
        _Pragma("unroll")                                                     \
        for (int k = 0; k < 4; ++k) {                                         \
            acc[0] = __builtin_amdgcn_mfma_f32_16x16x32_bf16(                 \
                afrag[0][k], bb[k], acc[0], 0, 0, 0);                         \
            acc[1] = __builtin_amdgcn_mfma_f32_16x16x32_bf16(                 \
                afrag[1][k], bb[k], acc[1], 0, 0, 0);                         \
        }                                                                     \
        /* Diagonal capture: wave-uniform, rare (2 tiles per wave total). */  \
        {                                                                     \
            unsigned u = (unsigned)(colbase - (rowbase + wid * 32));          \
            if (u < 32u) {                                                    \
                _Pragma("unroll")                                             \
                for (int ti2 = 0; ti2 < 2; ++ti2) {                           \
                    if (u == (unsigned)(ti2 * 16)) {                          \
                        _Pragma("unroll")                                     \
                        for (int r = 0; r < 4; ++r)                           \
                            if (l16 == quad * 4 + r)                          \
                                diag[colbase + l16] = acc[ti2][r];            \
                    }                                                         \
                }                                                             \
            }                                                                 \
        }                                                                     \
        int lab_c = lab[colbase + l16];                                       \
        _Pragma("unroll")                                                     \
        for (int ti = 0; ti < 2; ++ti) {                                      \
            _Pragma("unroll")                                                 \
            for (int r = 0; r < 4; ++r) {                                     \
                /* C/D: D[row=quad*4+r][col=l16] (m89/m91 verified) */        \
                int i = ti * 4 + r;                                           \
                float a = acc[ti][r];                                         \
                e_acc[i] += fast_exp2(__builtin_fmaf(a, C1F, C2F));           \
                float peq = (lab_c == lab_row[i]) ? 1.0f : 0.0f;              \
                p_acc[i] = __builtin_fmaf(peq, a, p_acc[i]);                  \
            }                                                                 \
        }                                                                     \
    }

// ---- 2) fused GEMM + e/p partials (coalesced reg-prefetch, no LDS) ----
__global__ __launch_bounds__(256, 2) void supcon_main(
    const unsigned short* __restrict__ Fb, const int* __restrict__ lab,
    float* __restrict__ e_part, float* __restrict__ p_part,
    float* __restrict__ diag)
{
    const int tid  = threadIdx.x;
    const int lane = tid & 63;
    const int wid  = tid >> 6;                   // wave owns 32 rows
    const int quad = lane >> 4;
    const int l16  = lane & 15;

    const int chunk   = blockIdx.x;
    const int rowbase = blockIdx.y * 128;
    const int colchunkbase = chunk * COLCHUNK;
    const int ctile0  = colchunkbase >> 4;

    const unsigned char* Fbc = (const unsigned char*)Fb;

    // A fragments (2 row-tiles x 4 k-chunks) — coalesced 1KB loads.
    bf16x8 afrag[2][4];
#pragma unroll
    for (int ti = 0; ti < 2; ++ti) {
        int rt = (rowbase >> 4) + wid * 2 + ti;
        const unsigned char* fa = Fbc + ((size_t)(rt * 4) << 10) + lane * 16;
#pragma unroll
        for (int k = 0; k < 4; ++k)
            afrag[ti][k] = *(const bf16x8*)(fa + (k << 10));
    }

    int lab_row[8];
#pragma unroll
    for (int ti = 0; ti < 2; ++ti)
#pragma unroll
        for (int r = 0; r < 4; ++r)
            lab_row[ti * 4 + r] = lab[rowbase + wid * 32 + ti * 16 + quad * 4 + r];

    float e_acc[8], p_acc[8];
#pragma unroll
    for (int i = 0; i < 8; ++i) { e_acc[i] = 0.0f; p_acc[i] = 0.0f; }

    // Double-state B registers, static names only (rule #20).
    bf16x8 b0[4], b1[4];
    LOADF(b0, 0);

    for (int t = 0; t < NT; t += 2) {
        // Prefetch next tile FIRST (issue-early), compute current (use-late):
        // the compiler keeps the loads in flight across COMPUTE and waits
        // only at the next body's first use.
        LOADF(b1, t + 1);
        COMPUTE(b0, t);
        if (t + 2 < NT) LOADF(b0, t + 2);
        COMPUTE(b1, t + 1);
    }

    // Waves own disjoint rows -> no cross-wave reduce, no LDS, no barrier.
    // Reduce over the 16 column-lanes (xor in l16 bits), then l16==0 lanes
    // (one per quad) write 8 rows each.
#pragma unroll
    for (int i = 0; i < 8; ++i) {
        float e = e_acc[i], p = p_acc[i];
#pragma unroll
        for (int m = 1; m < 16; m <<= 1) {
            e += __shfl_xor(e, m, 64);
            p += __shfl_xor(p, m, 64);
        }
        if (l16 == 0) {
            int row = rowbase + wid * 32 + (i >> 2) * 16 + quad * 4 + (i & 3);
            e_part[(size_t)chunk * BB + row] = e;
            p_part[(size_t)chunk * BB + row] = p;
        }
    }
}

// ---- 3) e/p partials -> scalar loss ----
__global__ __launch_bounds__(256) void supcon_reduce(
    const float* __restrict__ e_part, const float* __restrict__ p_part,
    const int* __restrict__ labels, const float* __restrict__ diag,
    float* __restrict__ accbuf, float* __restrict__ out)
{
    // Exact per-class counts over the whole batch (labels in [0,100)).
    __shared__ int cnt[128];
    if (threadIdx.x < 128) cnt[threadIdx.x] = 0;
    __syncthreads();
    for (int i = threadIdx.x; i < BB; i += 256)
        atomicAdd(&cnt[labels[i]], 1);
    __syncthreads();

    int row = blockIdx.x * 256 + threadIdx.x;    // grid 32
    float e = 0.f, p = 0.f;
#pragma unroll
    for (int c = 0; c < NC; ++c) {
        size_t idx = (size_t)c * BB + row;
        e += e_part[idx]; p += p_part[idx];
    }
    // exact diagonal removal (e: same exp2 instruction on same input as main)
    float d = diag[row];
    e -= fast_exp2(__builtin_fmaf(d, C1F, C2F));
    p -= d;
    int n_i = cnt[labels[row]] - 1;              // integer-exact positive count

    float contrib = 0.f, vld = 0.f;
    if (n_i > 0) {
        vld = 1.0f;
        contrib = -(p * TEMP_INV / (float)n_i - MSHIFT - logf(e));
    }
#pragma unroll
    for (int m = 1; m < 64; m <<= 1) {
        contrib += __shfl_xor(contrib, m, 64);
        vld     += __shfl_xor(vld, m, 64);
    }
    __shared__ float rl[4], rv[4];
    int lane = threadIdx.x & 63, w = threadIdx.x >> 6;
    if (lane == 0) { rl[w] = contrib; rv[w] = vld; }
    __syncthreads();
    if (threadIdx.x == 0) {
        float L = rl[0] + rl[1] + rl[2] + rl[3];
        float V = rv[0] + rv[1] + rv[2] + rv[3];
        atomicAdd(&accbuf[0], L);
        atomicAdd(&accbuf[1], V);
        __threadfence();
        unsigned t = atomicAdd((unsigned*)accbuf + 2, 1u);
        if (t == 31u) {                      // last block: all adds fenced+done
            float Ls = atomicAdd(&accbuf[0], 0.0f);
            float Vs = atomicAdd(&accbuf[1], 0.0f);
            out[0] = (Vs > 0.5f) ? (Ls / Vs) : 0.0f;
        }
    }
}

extern "C" void kernel_launch(void* const* d_in, const int* in_sizes, int n_in,
                              void* d_out, int out_size, void* d_ws, size_t ws_size,
                              hipStream_t stream)
{
    const void* Fin = d_in[0];
    const void* Lin = d_in[1];

    // ws layout (~3.1 MB)
    unsigned short* frag = (unsigned short*)d_ws;                         // 2 MB fragment-order bf16
    int*   lab      = (int*)((char*)d_ws + (size_t)BB * DD * 2);          // 32 KB
    float* e_part   = (float*)((char*)lab + (size_t)BB * 4);              // NC*B floats (512 KB)
    float* p_part   = e_part + (size_t)NC * BB;                           // 512 KB
    float* diag     = p_part + (size_t)NC * BB;                           // B floats
    float* accbuf   = diag + BB;                                          // 3 slots

    supcon_convert<<<BB * DD / 8 / 256, 256, 0, stream>>>(Fin, Lin, frag, lab, accbuf);

    dim3 grid(NC, BB / 128);
    supcon_main<<<grid, 256, 0, stream>>>(frag, lab, e_part, p_part, diag);

    supcon_reduce<<<32, 256, 0, stream>>>(e_part, p_part, lab, diag, accbuf, (float*)d_out);
}